// Round 6
// baseline (35.359 us; speedup 1.0000x reference)
//
#include <hip/hip_runtime.h>
#include <hip/hip_bf16.h>

typedef __bf16 bf16_t;
typedef __bf16 bf16x8 __attribute__((ext_vector_type(8)));
typedef float  f32x2  __attribute__((ext_vector_type(2)));
typedef float  f32x4  __attribute__((ext_vector_type(4)));

static constexpr int Mtot = 4096;   // B*S
static constexpr int Ntot = 1024;   // H*A
static constexpr int Ktot = 1024;   // F
static constexpr int NT   = Ktot / 64;   // 16 K-steps of BK=64

// out[b,s,h,a] = sum_f value_input[b,s,f] * v_w[h,f,a]
// (reference softmax over q integrates to exactly 1 in the final q-contraction,
//  so the whole op reduces to the value-projection GEMM)
//
// Single fused kernel. BM=BN=BK=64; grid 1024 blocks (4/CU); 4 waves (2x2,
// wave-tile 32x32). A reg-staged fp32->bf16; B reg-staged with in-register
// transpose ([k][a] -> [n][k]) + cvt. LDS tiles [row][64k] (128-B rows),
// 16B-chunk XOR-swizzle on BOTH write and read (write-side swizzle legal:
// ds_write, not global_load_lds). All wave LDS ops cover 32 banks optimally.
__global__ __launch_bounds__(256, 4)
void fused_vproj_kernel(const float* __restrict__ A, const float* __restrict__ W,
                        float* __restrict__ C)
{
    __shared__ bf16_t As[2][64 * 64];   // [row][k]
    __shared__ bf16_t Bs[2][64 * 64];   // [n=a][k]

    const int t = threadIdx.x, lane = t & 63, wave = t >> 6;
    const int wm = wave & 1, wn = wave >> 1;

    // XCD swizzle (bijective, 1024%8==0): XCD x owns g in [128x,128x+128)
    // = 8 contiguous M-panels x all 16 N-tiles (A-slice 2 MB L2-resident).
    const int g  = (blockIdx.x & 7) * 128 + (blockIdx.x >> 3);
    const int by = g >> 4, bx = g & 15;
    const int bm = by * 64, bn = bx * 64;          // head = bx (BN = A = 64)

    const int lrow = lane & 15, lq = lane >> 4;

    // B staging coords: thread owns 8k x 2a micro-tile
    const int ac = t & 31;         // a-pair: a = 2ac, 2ac+1
    const int ko = t >> 5;         // k-octet 0..7: k = 8ko..8ko+7
    const float* const wbase = W + (size_t)bx * (Ktot * 64) + (size_t)(8 * ko) * 64 + 2 * ac;

    f32x4 aA[2][2];    // A: 2 groups of 8 floats (2 x f32x4 each)
    f32x2 bB[8];       // B: 8 rows of f32x2

    auto LOAD = [&](int k0) {
#pragma unroll
        for (int j = 0; j < 2; ++j) {
            const int idx8 = j * 256 + t;
            const int row = idx8 >> 3, o8 = idx8 & 7;
            const float* ap = A + (size_t)(bm + row) * Ktot + k0 + o8 * 8;
            aA[j][0] = *(const f32x4*)(ap);
            aA[j][1] = *(const f32x4*)(ap + 4);
        }
        const float* wp = wbase + (size_t)k0 * 64;
#pragma unroll
        for (int j = 0; j < 8; ++j)
            bB[j] = *(const f32x2*)(wp + (size_t)j * 64);
    };

    auto STORE = [&](int buf) {
#pragma unroll
        for (int j = 0; j < 2; ++j) {
            const int idx8 = j * 256 + t;
            const int row = idx8 >> 3, o8 = idx8 & 7;
            bf16x8 v = {(bf16_t)aA[j][0][0], (bf16_t)aA[j][0][1],
                        (bf16_t)aA[j][0][2], (bf16_t)aA[j][0][3],
                        (bf16_t)aA[j][1][0], (bf16_t)aA[j][1][1],
                        (bf16_t)aA[j][1][2], (bf16_t)aA[j][1][3]};
            *(bf16x8*)&As[buf][row * 64 + (o8 ^ (row & 7)) * 8] = v;
        }
#pragma unroll
        for (int e = 0; e < 2; ++e) {
            const int n = 2 * ac + e;
            bf16x8 v = {(bf16_t)bB[0][e], (bf16_t)bB[1][e],
                        (bf16_t)bB[2][e], (bf16_t)bB[3][e],
                        (bf16_t)bB[4][e], (bf16_t)bB[5][e],
                        (bf16_t)bB[6][e], (bf16_t)bB[7][e]};
            *(bf16x8*)&Bs[buf][n * 64 + (ko ^ (n & 7)) * 8] = v;
        }
    };

    f32x4 acc[2][2];
#pragma unroll
    for (int mf = 0; mf < 2; ++mf)
#pragma unroll
        for (int nf = 0; nf < 2; ++nf) {
            f32x4 z = {0.f, 0.f, 0.f, 0.f};
            acc[mf][nf] = z;
        }

    auto COMPUTE = [&](int cur) {
#pragma unroll
        for (int kk = 0; kk < 2; ++kk) {
            const int c16 = kk * 4 + lq;    // k-chunk 0..7
            bf16x8 af[2], bfr[2];
#pragma unroll
            for (int mf = 0; mf < 2; ++mf) {
                const int R = wm * 32 + mf * 16 + lrow;
                af[mf] = *(const bf16x8*)&As[cur][R * 64 + (c16 ^ (R & 7)) * 8];
            }
#pragma unroll
            for (int nf = 0; nf < 2; ++nf) {
                const int R = wn * 32 + nf * 16 + lrow;
                bfr[nf] = *(const bf16x8*)&Bs[cur][R * 64 + (c16 ^ (R & 7)) * 8];
            }
            __builtin_amdgcn_s_setprio(1);
#pragma unroll
            for (int mf = 0; mf < 2; ++mf)
#pragma unroll
                for (int nf = 0; nf < 2; ++nf)
                    acc[mf][nf] = __builtin_amdgcn_mfma_f32_16x16x32_bf16(
                        af[mf], bfr[nf], acc[mf][nf], 0, 0, 0);
            __builtin_amdgcn_s_setprio(0);
        }
    };

    // prologue
    LOAD(0);
    STORE(0);
    __syncthreads();

    for (int tI = 0; tI < NT; ++tI) {
        const int cur = tI & 1;
        if (tI + 1 < NT) LOAD((tI + 1) * 64);   // vmcnt naturally sinks to STORE
        COMPUTE(cur);
        __syncthreads();                        // all waves done reading buf cur
        if (tI + 1 < NT) STORE(cur ^ 1);
        __syncthreads();                        // writes visible for next COMPUTE
    }

    // epilogue: C/D layout col = lane&15, row = (lane>>4)*4 + i
#pragma unroll
    for (int mf = 0; mf < 2; ++mf) {
        const int row0 = bm + wm * 32 + mf * 16 + (lq << 2);
#pragma unroll
        for (int nf = 0; nf < 2; ++nf) {
            const int col = bn + wn * 32 + nf * 16 + lrow;
#pragma unroll
            for (int i = 0; i < 4; ++i)
                C[(size_t)(row0 + i) * Ntot + col] = acc[mf][nf][i];
        }
    }
}

extern "C" void kernel_launch(void* const* d_in, const int* in_sizes, int n_in,
                              void* d_out, int out_size, void* d_ws, size_t ws_size,
                              hipStream_t stream) {
    (void)in_sizes; (void)n_in; (void)d_ws; (void)ws_size; (void)out_size;
    // setup_inputs order: key_input, query_input, value_input, q_w, k_w, v_w
    const float* V  = (const float*)d_in[2];   // [B,S,F] = [M][K]
    const float* Vw = (const float*)d_in[5];   // [H,F,A]
    float* out      = (float*)d_out;           // [B,S,H,A] = [M][N]

    const int nwg = (Mtot / 64) * (Ntot / 64);  // 64 * 16 = 1024 blocks
    hipLaunchKernelGGL(fused_vproj_kernel, dim3(nwg), dim3(256), 0, stream,
                       V, Vw, out);
}